// Round 2
// baseline (1446.749 us; speedup 1.0000x reference)
//
#include <hip/hip_runtime.h>
#include <stdint.h>

#define B_ 256
#define T_ 512
#define F_ 128
#define U_ 256
#define H_ 64
#define G4U (4 * U_)

typedef __attribute__((ext_vector_type(8))) short short8;
typedef __attribute__((ext_vector_type(4))) float f32x4;
typedef unsigned long long ull;

__device__ __forceinline__ uint16_t f2bf(float f) {
  uint32_t u = __builtin_bit_cast(uint32_t, f);
  u += 0x7fffu + ((u >> 16) & 1u);
  return (uint16_t)(u >> 16);
}
__device__ __forceinline__ float sigm(float z) {
  return 1.0f / (1.0f + __expf(-z));
}

// ---------------------------------------------------------------------------
// Persistent LSTM kernel.
// Grid: 128 WGs x 256 threads. bg = blockIdx&15 (16 batch rows each),
// ug = blockIdx>>4 (32 hidden units each). Group {bg + 16*ug, ug=0..7}
// exchanges h through hbuf (double-buffered) + per-group counter via
// agent-scope relaxed atomics (coherence-point ops on gfx950).
// Weights (rec_kernel slice 256x128 + kernel slice 128x128) live in VGPRs
// as pre-packed bf16 MFMA B-fragments.
// ---------------------------------------------------------------------------
__global__ __launch_bounds__(256, 1) void lstm_kernel(
    const float* __restrict__ x, const float* __restrict__ kern,
    const float* __restrict__ rker, const float* __restrict__ bias,
    uint16_t* __restrict__ seq, uint16_t* __restrict__ hbuf,
    uint32_t* __restrict__ ctr)
{
  const int tid  = threadIdx.x;
  const int lane = tid & 63;
  const int wv   = tid >> 6;
  const int bg   = blockIdx.x & 15;
  const int ug   = blockIdx.x >> 4;

  // A-fragment staging, layout: [ktile][lane][8 bf16];
  // fragment read = ds_read_b128 at byte (kt*1024 + lane*16)  (conflict-free)
  __shared__ __align__(16) uint16_t x_stage[4][64][8];   // 4 KB  (16 rows x 128 feat)
  __shared__ __align__(16) uint16_t h_stage[8][64][8];   // 8 KB  (16 rows x 256 units)
  __shared__ __align__(16) float    z_stage[128][20];    // 10 KB, stride 20 pad

  // ---- preload weights into registers as B-fragments ----
  short8 wf[2][8];   // rec_kernel frags: [coltile][ktile] (K=256)
  short8 kf[2][4];   // kernel frags:     [coltile][ktile] (K=128)
  float  bias_r[2];
  #pragma unroll
  for (int i2 = 0; i2 < 2; ++i2) {
    const int ct   = wv * 2 + i2;
    const int cloc = ct * 16 + (lane & 15);                     // local col 0..127
    const int gcol = (cloc >> 5) * U_ + ug * 32 + (cloc & 31);  // i|f|g|o blocks
    bias_r[i2] = bias[gcol];
    #pragma unroll
    for (int kt = 0; kt < 8; ++kt) {
      short8 v;
      #pragma unroll
      for (int j = 0; j < 8; ++j) {
        const int k = kt * 32 + (lane >> 4) * 8 + j;
        v[j] = (short)f2bf(rker[(size_t)k * G4U + gcol]);
      }
      wf[i2][kt] = v;
    }
    #pragma unroll
    for (int kt = 0; kt < 4; ++kt) {
      short8 v;
      #pragma unroll
      for (int j = 0; j < 8; ++j) {
        const int k = kt * 32 + (lane >> 4) * 8 + j;
        v[j] = (short)f2bf(kern[(size_t)k * G4U + gcol]);
      }
      kf[i2][kt] = v;
    }
  }

  // ---- roles ----
  // x-staging: thread owns flat 16B of x_stage (bytes tid*16): row/feature:
  const int xrow = tid & 15;
  const int xfb  = (tid >> 6) * 32 + ((tid >> 4) & 3) * 8;    // feature base
  // h-exchange: thread owns flat 32B of h_stage (bytes tid*32):
  //   chunk0 = h[row0][ub0..ub0+7], chunk1 = h[row0+1][ub0..ub0+7]
  const int hrow0 = (tid * 2) & 15;                            // even
  const int hub0  = (tid >> 5) * 32 + ((tid >> 3) & 3) * 8;    // unit base
  // gate-eval: thread owns units {u0,u0+1} of row gr
  const int gr  = tid & 15;
  const int u0  = (tid >> 4) * 2;

  float cst0 = 0.f, cst1 = 0.f;   // persistent cell state (fp32)

  // ---- stage x for t=0 ----
  float xp[8];
  {
    const float* p = x + ((size_t)(bg * 16 + xrow) * T_ + 0) * F_ + xfb;
    #pragma unroll
    for (int j = 0; j < 8; ++j) xp[j] = p[j];
    uint16_t* d = (uint16_t*)x_stage + tid * 8;
    #pragma unroll
    for (int j = 0; j < 8; ++j) d[j] = f2bf(xp[j]);
  }
  __syncthreads();

  for (int t = 0; t < T_; ++t) {
    // (a) z_x = bias + x_t @ kernel   (independent of h -> overlaps peer wait)
    f32x4 acc0 = {bias_r[0], bias_r[0], bias_r[0], bias_r[0]};
    f32x4 acc1 = {bias_r[1], bias_r[1], bias_r[1], bias_r[1]};
    #pragma unroll
    for (int kt = 0; kt < 4; ++kt) {
      short8 a = *(const short8*)&x_stage[kt][lane][0];
      acc0 = __builtin_amdgcn_mfma_f32_16x16x32_bf16(a, kf[0][kt], acc0, 0, 0, 0);
      acc1 = __builtin_amdgcn_mfma_f32_16x16x32_bf16(a, kf[1][kt], acc1, 0, 0, 0);
    }
    // issue x loads for t+1 (consumed at phase (g))
    {
      const int tn = (t + 1 < T_) ? t + 1 : t;
      const float* p = x + ((size_t)(bg * 16 + xrow) * T_ + tn) * F_ + xfb;
      #pragma unroll
      for (int j = 0; j < 8; ++j) xp[j] = p[j];
    }
    // (b) wait until all 8 group members published h_{t-1}
    {
      const uint32_t target = 8u * (uint32_t)t;
      while (__hip_atomic_load(&ctr[bg], __ATOMIC_RELAXED, __HIP_MEMORY_SCOPE_AGENT) < target)
        __builtin_amdgcn_s_sleep(2);
      __builtin_amdgcn_sched_barrier(0);   // keep hbuf loads below the poll
    }
    // (c) exchange: h_{t-1}[16 x 256] -> h_stage (full 8KB, 32B/thread)
    {
      const int cur = t & 1;
      const ull* p = (const ull*)(hbuf + (size_t)cur * (B_ * U_)
                                  + (size_t)(bg * 16 + hrow0) * U_ + hub0);
      ull a0 = __hip_atomic_load(p,      __ATOMIC_RELAXED, __HIP_MEMORY_SCOPE_AGENT);
      ull a1 = __hip_atomic_load(p + 1,  __ATOMIC_RELAXED, __HIP_MEMORY_SCOPE_AGENT);
      ull a2 = __hip_atomic_load(p + 64, __ATOMIC_RELAXED, __HIP_MEMORY_SCOPE_AGENT);   // +1 row
      ull a3 = __hip_atomic_load(p + 65, __ATOMIC_RELAXED, __HIP_MEMORY_SCOPE_AGENT);
      ull* d = (ull*)h_stage + (size_t)tid * 4;   // flat-contiguous: conflict-free
      d[0] = a0; d[1] = a1; d[2] = a2; d[3] = a3;
    }
    __syncthreads();   // (d) h_stage ready
    // (e) z += h_{t-1} @ rec_kernel
    #pragma unroll
    for (int kt = 0; kt < 8; ++kt) {
      short8 a = *(const short8*)&h_stage[kt][lane][0];
      acc0 = __builtin_amdgcn_mfma_f32_16x16x32_bf16(a, wf[0][kt], acc0, 0, 0, 0);
      acc1 = __builtin_amdgcn_mfma_f32_16x16x32_bf16(a, wf[1][kt], acc1, 0, 0, 0);
    }
    {
      const int c0 = (wv * 2 + 0) * 16 + (lane & 15);
      const int c1 = (wv * 2 + 1) * 16 + (lane & 15);
      const int r0 = (lane >> 4) * 4;
      *(f32x4*)&z_stage[c0][r0] = acc0;   // z_stage[col][row]
      *(f32x4*)&z_stage[c1][r0] = acc1;
    }
    __syncthreads();   // (f) z ready
    // (g) gates + state update + publish h_t; also stage x_{t+1}
    {
      const float zi0 = z_stage[u0][gr],      zi1 = z_stage[u0 + 1][gr];
      const float zf0 = z_stage[32 + u0][gr], zf1 = z_stage[33 + u0][gr];
      const float zg0 = z_stage[64 + u0][gr], zg1 = z_stage[65 + u0][gr];
      const float zo0 = z_stage[96 + u0][gr], zo1 = z_stage[97 + u0][gr];
      const float i0 = sigm(zi0), i1 = sigm(zi1);
      const float f0 = sigm(zf0), f1 = sigm(zf1);
      const float g0 = zg0 * sigm(zg0), g1 = zg1 * sigm(zg1);
      const float o0 = sigm(zo0), o1 = sigm(zo1);
      cst0 = f0 * cst0 + i0 * g0;
      cst1 = f1 * cst1 + i1 * g1;
      const float h0 = o0 * (cst0 * sigm(cst0));
      const float h1 = o1 * (cst1 * sigm(cst1));
      const uint32_t packed = (uint32_t)f2bf(h0) | ((uint32_t)f2bf(h1) << 16);
      const int nxt = (t + 1) & 1;
      uint32_t* hd = (uint32_t*)(hbuf + (size_t)nxt * (B_ * U_)
                                 + (size_t)(bg * 16 + gr) * U_ + ug * 32 + u0);
      __hip_atomic_store(hd, packed, __ATOMIC_RELAXED, __HIP_MEMORY_SCOPE_AGENT);
      *(uint32_t*)(seq + ((size_t)(bg * 16 + gr) * T_ + t) * U_ + ug * 32 + u0) = packed;
      uint16_t* d = (uint16_t*)x_stage + tid * 8;
      #pragma unroll
      for (int j = 0; j < 8; ++j) d[j] = f2bf(xp[j]);
    }
    __syncthreads();   // (h) drains vmem stores (implies vmcnt(0)) before signal
    if (tid == 0)
      (void)__hip_atomic_fetch_add(&ctr[bg], 1u, __ATOMIC_RELAXED, __HIP_MEMORY_SCOPE_AGENT);
  }
}

// ---------------------------------------------------------------------------
// Head GEMM: partials[g][b][h] = seq[b, g-chunk] @ w_out[g-chunk, h]
// 64 WGs, K-chunk = 2048 (8 timesteps). All-register MFMA, no LDS.
// ---------------------------------------------------------------------------
__global__ __launch_bounds__(256, 1) void head_kernel(
    const uint16_t* __restrict__ seq, const float* __restrict__ w_out,
    float* __restrict__ partials)
{
  const int g    = blockIdx.x;
  const int tid  = threadIdx.x;
  const int lane = tid & 63;
  const int wv   = tid >> 6;

  f32x4 acc[4][4];
  #pragma unroll
  for (int i = 0; i < 4; ++i)
    #pragma unroll
    for (int c = 0; c < 4; ++c) acc[i][c] = (f32x4){0.f, 0.f, 0.f, 0.f};

  for (int ks = 0; ks < 64; ++ks) {
    const int krow = g * 2048 + ks * 32 + (lane >> 4) * 8;
    short8 bf[4];
    #pragma unroll
    for (int c = 0; c < 4; ++c) {
      short8 v;
      #pragma unroll
      for (int j = 0; j < 8; ++j)
        v[j] = (short)f2bf(w_out[(size_t)(krow + j) * H_ + c * 16 + (lane & 15)]);
      bf[c] = v;
    }
    #pragma unroll
    for (int i = 0; i < 4; ++i) {
      const int b = (wv * 4 + i) * 16 + (lane & 15);
      short8 a = *(const short8*)(seq + (size_t)b * (T_ * U_) + krow);
      #pragma unroll
      for (int c = 0; c < 4; ++c)
        acc[i][c] = __builtin_amdgcn_mfma_f32_16x16x32_bf16(a, bf[c], acc[i][c], 0, 0, 0);
    }
  }
  #pragma unroll
  for (int i = 0; i < 4; ++i)
    #pragma unroll
    for (int c = 0; c < 4; ++c)
      #pragma unroll
      for (int r = 0; r < 4; ++r) {
        const int b = wv * 64 + i * 16 + (lane >> 4) * 4 + r;
        partials[((size_t)g * B_ + b) * H_ + c * 16 + (lane & 15)] = acc[i][c][r];
      }
}

__global__ void reduce_kernel(const float* __restrict__ partials,
                              const float* __restrict__ b_out,
                              float* __restrict__ out)
{
  const int i = blockIdx.x * 256 + threadIdx.x;   // b*64 + h
  float s = b_out[i & (H_ - 1)];
  #pragma unroll 8
  for (int g = 0; g < 64; ++g) s += partials[(size_t)g * (B_ * H_) + i];
  out[i] = s;
}

// ---------------------------------------------------------------------------
extern "C" void kernel_launch(void* const* d_in, const int* in_sizes, int n_in,
                              void* d_out, int out_size, void* d_ws, size_t ws_size,
                              hipStream_t stream) {
  (void)in_sizes; (void)n_in; (void)out_size; (void)ws_size;
  const float* x     = (const float*)d_in[0];
  const float* kern  = (const float*)d_in[1];
  const float* rker  = (const float*)d_in[2];
  const float* bias  = (const float*)d_in[3];
  const float* w_out = (const float*)d_in[4];
  const float* b_out = (const float*)d_in[5];
  float* out = (float*)d_out;

  char* ws = (char*)d_ws;
  const size_t seq_bytes  = (size_t)B_ * T_ * U_ * 2;        // 64 MB
  const size_t hbuf_bytes = (size_t)2 * B_ * U_ * 2;         // 256 KB
  uint16_t* seq      = (uint16_t*)ws;
  uint16_t* hbuf     = (uint16_t*)(ws + seq_bytes);
  uint32_t* ctr      = (uint32_t*)(ws + seq_bytes + hbuf_bytes);
  float*    partials = (float*)(ws + seq_bytes + hbuf_bytes + 256);   // 4 MB

  // per-launch re-init (graph replays don't re-poison): h_0 = 0, counters = 0
  hipMemsetAsync(hbuf, 0, (size_t)B_ * U_ * 2, stream);   // buffer 0 only
  hipMemsetAsync(ctr, 0, 64, stream);

  lstm_kernel<<<128, 256, 0, stream>>>(x, kern, rker, bias, seq, hbuf, ctr);
  head_kernel<<<64, 256, 0, stream>>>(seq, w_out, partials);
  reduce_kernel<<<64, 256, 0, stream>>>(partials, b_out, out);
}

// Round 3
// 1288.953 us; speedup vs baseline: 1.1224x; 1.1224x over previous
//
#include <hip/hip_runtime.h>
#include <stdint.h>

#define B_ 256
#define T_ 512
#define F_ 128
#define U_ 256
#define H_ 64
#define G4U (4 * U_)

typedef __attribute__((ext_vector_type(8))) short short8;
typedef __attribute__((ext_vector_type(4))) float f32x4;
typedef unsigned long long ull;

__device__ __forceinline__ uint16_t f2bf(float f) {
  uint32_t u = __builtin_bit_cast(uint32_t, f);
  u += 0x7fffu + ((u >> 16) & 1u);
  return (uint16_t)(u >> 16);
}
__device__ __forceinline__ float sigm(float z) {
  return 1.0f / (1.0f + __expf(-z));
}

// ---------------------------------------------------------------------------
// Persistent LSTM kernel.
// Grid: 128 WGs x 256 threads. bg = blockIdx&15 (16 batch rows each),
// ug = blockIdx>>4 (32 hidden units each). Group {bg + 16*ug, ug=0..7}
// exchanges h through hbuf (double-buffered).
// Sync protocol (this round): per-producer FLAG STORES flg[bg*8+ug] = t+1
// (agent-scope relaxed atomic store, issued after __syncthreads drained the
// h stores to the coherence point). No RMW -> no serialization at the mall.
// Consumers poll the 8 flags with one coalesced 32B load per wave per iter.
// seq store moved AFTER the signal (off the critical path).
// ---------------------------------------------------------------------------
__global__ __launch_bounds__(256, 1) void lstm_kernel(
    const float* __restrict__ x, const float* __restrict__ kern,
    const float* __restrict__ rker, const float* __restrict__ bias,
    uint16_t* __restrict__ seq, uint16_t* __restrict__ hbuf,
    uint32_t* __restrict__ flg)
{
  const int tid  = threadIdx.x;
  const int lane = tid & 63;
  const int wv   = tid >> 6;
  const int bg   = blockIdx.x & 15;
  const int ug   = blockIdx.x >> 4;

  // A-fragment staging, layout: [ktile][lane][8 bf16];
  // fragment read = ds_read_b128 at byte (kt*1024 + lane*16)  (conflict-free)
  __shared__ __align__(16) uint16_t x_stage[4][64][8];   // 4 KB  (16 rows x 128 feat)
  __shared__ __align__(16) uint16_t h_stage[8][64][8];   // 8 KB  (16 rows x 256 units)
  __shared__ __align__(16) float    z_stage[128][20];    // 10 KB, stride 20 pad

  // ---- preload weights into registers as B-fragments ----
  short8 wf[2][8];   // rec_kernel frags: [coltile][ktile] (K=256)
  short8 kf[2][4];   // kernel frags:     [coltile][ktile] (K=128)
  float  bias_r[2];
  #pragma unroll
  for (int i2 = 0; i2 < 2; ++i2) {
    const int ct   = wv * 2 + i2;
    const int cloc = ct * 16 + (lane & 15);                     // local col 0..127
    const int gcol = (cloc >> 5) * U_ + ug * 32 + (cloc & 31);  // i|f|g|o blocks
    bias_r[i2] = bias[gcol];
    #pragma unroll
    for (int kt = 0; kt < 8; ++kt) {
      short8 v;
      #pragma unroll
      for (int j = 0; j < 8; ++j) {
        const int k = kt * 32 + (lane >> 4) * 8 + j;
        v[j] = (short)f2bf(rker[(size_t)k * G4U + gcol]);
      }
      wf[i2][kt] = v;
    }
    #pragma unroll
    for (int kt = 0; kt < 4; ++kt) {
      short8 v;
      #pragma unroll
      for (int j = 0; j < 8; ++j) {
        const int k = kt * 32 + (lane >> 4) * 8 + j;
        v[j] = (short)f2bf(kern[(size_t)k * G4U + gcol]);
      }
      kf[i2][kt] = v;
    }
  }

  // ---- roles ----
  const int xrow = tid & 15;                                   // x-staging row
  const int xfb  = (tid >> 6) * 32 + ((tid >> 4) & 3) * 8;     // feature base
  const int hrow0 = (tid * 2) & 15;                            // h-exchange rows (even, +1)
  const int hub0  = (tid >> 5) * 32 + ((tid >> 3) & 3) * 8;    // unit base
  const int gr  = tid & 15;                                    // gate row
  const int u0  = (tid >> 4) * 2;                              // gate unit pair

  float cst0 = 0.f, cst1 = 0.f;   // persistent cell state (fp32)

  // ---- stage x for t=0 ----
  float xp[8];
  {
    const float* p = x + ((size_t)(bg * 16 + xrow) * T_ + 0) * F_ + xfb;
    #pragma unroll
    for (int j = 0; j < 8; ++j) xp[j] = p[j];
    uint16_t* d = (uint16_t*)x_stage + tid * 8;
    #pragma unroll
    for (int j = 0; j < 8; ++j) d[j] = f2bf(xp[j]);
  }
  __syncthreads();

  for (int t = 0; t < T_; ++t) {
    // (a) z_x = bias + x_t @ kernel   (independent of h -> overlaps peer wait)
    f32x4 acc0 = {bias_r[0], bias_r[0], bias_r[0], bias_r[0]};
    f32x4 acc1 = {bias_r[1], bias_r[1], bias_r[1], bias_r[1]};
    #pragma unroll
    for (int kt = 0; kt < 4; ++kt) {
      short8 a = *(const short8*)&x_stage[kt][lane][0];
      acc0 = __builtin_amdgcn_mfma_f32_16x16x32_bf16(a, kf[0][kt], acc0, 0, 0, 0);
      acc1 = __builtin_amdgcn_mfma_f32_16x16x32_bf16(a, kf[1][kt], acc1, 0, 0, 0);
    }
    // issue x loads for t+1 (consumed at phase (g))
    {
      const int tn = (t + 1 < T_) ? t + 1 : t;
      const float* p = x + ((size_t)(bg * 16 + xrow) * T_ + tn) * F_ + xfb;
      #pragma unroll
      for (int j = 0; j < 8; ++j) xp[j] = p[j];
    }
    // (b) wait until all 8 group members published h_{t-1}:
    // each lane spins on one of the 8 flag words (one 32B line per wave/iter)
    {
      const uint32_t* fp = &flg[bg * 8 + (lane & 7)];
      while (__hip_atomic_load(fp, __ATOMIC_RELAXED, __HIP_MEMORY_SCOPE_AGENT) < (uint32_t)t)
        __builtin_amdgcn_s_sleep(1);
      __builtin_amdgcn_sched_barrier(0);   // keep hbuf loads below the poll
    }
    // (c) exchange: h_{t-1}[16 x 256] -> h_stage (full 8KB, 32B/thread)
    {
      const int cur = t & 1;
      const ull* p = (const ull*)(hbuf + (size_t)cur * (B_ * U_)
                                  + (size_t)(bg * 16 + hrow0) * U_ + hub0);
      ull a0 = __hip_atomic_load(p,      __ATOMIC_RELAXED, __HIP_MEMORY_SCOPE_AGENT);
      ull a1 = __hip_atomic_load(p + 1,  __ATOMIC_RELAXED, __HIP_MEMORY_SCOPE_AGENT);
      ull a2 = __hip_atomic_load(p + 64, __ATOMIC_RELAXED, __HIP_MEMORY_SCOPE_AGENT);   // +1 row
      ull a3 = __hip_atomic_load(p + 65, __ATOMIC_RELAXED, __HIP_MEMORY_SCOPE_AGENT);
      ull* d = (ull*)h_stage + (size_t)tid * 4;   // flat-contiguous: conflict-free
      d[0] = a0; d[1] = a1; d[2] = a2; d[3] = a3;
    }
    __syncthreads();   // (d) h_stage ready
    // (e) z += h_{t-1} @ rec_kernel
    #pragma unroll
    for (int kt = 0; kt < 8; ++kt) {
      short8 a = *(const short8*)&h_stage[kt][lane][0];
      acc0 = __builtin_amdgcn_mfma_f32_16x16x32_bf16(a, wf[0][kt], acc0, 0, 0, 0);
      acc1 = __builtin_amdgcn_mfma_f32_16x16x32_bf16(a, wf[1][kt], acc1, 0, 0, 0);
    }
    {
      const int c0 = (wv * 2 + 0) * 16 + (lane & 15);
      const int c1 = (wv * 2 + 1) * 16 + (lane & 15);
      const int r0 = (lane >> 4) * 4;
      *(f32x4*)&z_stage[c0][r0] = acc0;   // z_stage[col][row]
      *(f32x4*)&z_stage[c1][r0] = acc1;
    }
    __syncthreads();   // (f) z ready
    // (g) gates + state update + publish h_t; also stage x_{t+1}
    uint32_t packed;
    {
      const float zi0 = z_stage[u0][gr],      zi1 = z_stage[u0 + 1][gr];
      const float zf0 = z_stage[32 + u0][gr], zf1 = z_stage[33 + u0][gr];
      const float zg0 = z_stage[64 + u0][gr], zg1 = z_stage[65 + u0][gr];
      const float zo0 = z_stage[96 + u0][gr], zo1 = z_stage[97 + u0][gr];
      const float i0 = sigm(zi0), i1 = sigm(zi1);
      const float f0 = sigm(zf0), f1 = sigm(zf1);
      const float g0 = zg0 * sigm(zg0), g1 = zg1 * sigm(zg1);
      const float o0 = sigm(zo0), o1 = sigm(zo1);
      cst0 = f0 * cst0 + i0 * g0;
      cst1 = f1 * cst1 + i1 * g1;
      const float h0 = o0 * (cst0 * sigm(cst0));
      const float h1 = o1 * (cst1 * sigm(cst1));
      packed = (uint32_t)f2bf(h0) | ((uint32_t)f2bf(h1) << 16);
      const int nxt = (t + 1) & 1;
      uint32_t* hd = (uint32_t*)(hbuf + (size_t)nxt * (B_ * U_)
                                 + (size_t)(bg * 16 + gr) * U_ + ug * 32 + u0);
      __hip_atomic_store(hd, packed, __ATOMIC_RELAXED, __HIP_MEMORY_SCOPE_AGENT);
      uint16_t* d = (uint16_t*)x_stage + tid * 8;
      #pragma unroll
      for (int j = 0; j < 8; ++j) d[j] = f2bf(xp[j]);
    }
    __syncthreads();   // (h) drains hbuf stores to coherence point (vmcnt(0))
    if (tid == 0)
      __hip_atomic_store(&flg[bg * 8 + ug], (uint32_t)(t + 1),
                         __ATOMIC_RELAXED, __HIP_MEMORY_SCOPE_AGENT);
    // seq store AFTER the signal -- off the critical path; next step's (h)
    // barrier drains it long after it has retired.
    *(uint32_t*)(seq + ((size_t)(bg * 16 + gr) * T_ + t) * U_ + ug * 32 + u0) = packed;
  }
}

// ---------------------------------------------------------------------------
// Head GEMM: partials[g][b][h] = seq[b, g-chunk] @ w_out[g-chunk, h]
// 64 WGs, K-chunk = 2048 (8 timesteps). All-register MFMA, no LDS.
// ---------------------------------------------------------------------------
__global__ __launch_bounds__(256, 1) void head_kernel(
    const uint16_t* __restrict__ seq, const float* __restrict__ w_out,
    float* __restrict__ partials)
{
  const int g    = blockIdx.x;
  const int tid  = threadIdx.x;
  const int lane = tid & 63;
  const int wv   = tid >> 6;

  f32x4 acc[4][4];
  #pragma unroll
  for (int i = 0; i < 4; ++i)
    #pragma unroll
    for (int c = 0; c < 4; ++c) acc[i][c] = (f32x4){0.f, 0.f, 0.f, 0.f};

  for (int ks = 0; ks < 64; ++ks) {
    const int krow = g * 2048 + ks * 32 + (lane >> 4) * 8;
    short8 bf[4];
    #pragma unroll
    for (int c = 0; c < 4; ++c) {
      short8 v;
      #pragma unroll
      for (int j = 0; j < 8; ++j)
        v[j] = (short)f2bf(w_out[(size_t)(krow + j) * H_ + c * 16 + (lane & 15)]);
      bf[c] = v;
    }
    #pragma unroll
    for (int i = 0; i < 4; ++i) {
      const int b = (wv * 4 + i) * 16 + (lane & 15);
      short8 a = *(const short8*)(seq + (size_t)b * (T_ * U_) + krow);
      #pragma unroll
      for (int c = 0; c < 4; ++c)
        acc[i][c] = __builtin_amdgcn_mfma_f32_16x16x32_bf16(a, bf[c], acc[i][c], 0, 0, 0);
    }
  }
  #pragma unroll
  for (int i = 0; i < 4; ++i)
    #pragma unroll
    for (int c = 0; c < 4; ++c)
      #pragma unroll
      for (int r = 0; r < 4; ++r) {
        const int b = wv * 64 + i * 16 + (lane >> 4) * 4 + r;
        partials[((size_t)g * B_ + b) * H_ + c * 16 + (lane & 15)] = acc[i][c][r];
      }
}

__global__ void reduce_kernel(const float* __restrict__ partials,
                              const float* __restrict__ b_out,
                              float* __restrict__ out)
{
  const int i = blockIdx.x * 256 + threadIdx.x;   // b*64 + h
  float s = b_out[i & (H_ - 1)];
  #pragma unroll 8
  for (int g = 0; g < 64; ++g) s += partials[(size_t)g * (B_ * H_) + i];
  out[i] = s;
}

// ---------------------------------------------------------------------------
extern "C" void kernel_launch(void* const* d_in, const int* in_sizes, int n_in,
                              void* d_out, int out_size, void* d_ws, size_t ws_size,
                              hipStream_t stream) {
  (void)in_sizes; (void)n_in; (void)out_size; (void)ws_size;
  const float* x     = (const float*)d_in[0];
  const float* kern  = (const float*)d_in[1];
  const float* rker  = (const float*)d_in[2];
  const float* bias  = (const float*)d_in[3];
  const float* w_out = (const float*)d_in[4];
  const float* b_out = (const float*)d_in[5];
  float* out = (float*)d_out;

  char* ws = (char*)d_ws;
  const size_t seq_bytes  = (size_t)B_ * T_ * U_ * 2;        // 64 MB
  const size_t hbuf_bytes = (size_t)2 * B_ * U_ * 2;         // 256 KB
  uint16_t* seq      = (uint16_t*)ws;
  uint16_t* hbuf     = (uint16_t*)(ws + seq_bytes);
  uint32_t* flg      = (uint32_t*)(ws + seq_bytes + hbuf_bytes);       // 16*8 u32
  float*    partials = (float*)(ws + seq_bytes + hbuf_bytes + 1024);   // 4 MB

  // per-launch re-init (graph replays don't re-poison): h_0 = 0, flags = 0
  hipMemsetAsync(hbuf, 0, (size_t)B_ * U_ * 2, stream);   // buffer 0 only
  hipMemsetAsync(flg, 0, 16 * 8 * 4, stream);

  lstm_kernel<<<128, 256, 0, stream>>>(x, kern, rker, bias, seq, hbuf, flg);
  head_kernel<<<64, 256, 0, stream>>>(seq, w_out, partials);
  reduce_kernel<<<64, 256, 0, stream>>>(partials, b_out, out);
}